// Round 15
// baseline (171.409 us; speedup 1.0000x reference)
//
#include <hip/hip_runtime.h>
#include <math.h>

typedef unsigned short u16;
typedef unsigned int u32;

// Problem constants
#define NPTS 16384
#define HID  512
#define TT   8
#define TE   64
#define NB   16
#define OUTC 218

typedef short s16x8 __attribute__((ext_vector_type(8)));   // 8 bf16 (4 VGPRs)
typedef float f32x4 __attribute__((ext_vector_type(4)));   // MFMA accumulator

__device__ __forceinline__ float bf2f(u16 u) {
  return __uint_as_float(((u32)u) << 16);
}
__device__ __forceinline__ u16 f2bf(float f) {
  u32 x = __float_as_uint(f);
  x += 0x7fffu + ((x >> 16) & 1u);
  return (u16)(x >> 16);
}
__device__ __forceinline__ float lrelu(float h) { return fmaxf(h, 0.02f * h); }

// dtype-adaptive external tensor access (f32 flag sniffed at runtime)
__device__ __forceinline__ float rd(const void* p, size_t i, bool f32) {
  return f32 ? ((const float*)p)[i] : bf2f(((const u16*)p)[i]);
}
__device__ __forceinline__ void wr(void* p, size_t i, bool f32, float v) {
  if (f32) ((float*)p)[i] = v;
  else ((u16*)p)[i] = f2bf(v);
}

// ---------------------------------------------------------------------------
// prep_conv (merged sniff + prep + W1-conv + segmax; one launch):
//   EVERY block first sniffs the dtype locally from pe[0:8192] (fp32 read as
//   bf16 pairs -> ~1/256 of low halves match the Inf/NaN exponent pattern;
//   finite bf16 never matches). 8KB L2-hot scan, no inter-block dependency.
//   Block 16 persists flag[0] for the downstream kernels.
//   blocks 0..7   : vprime[t][j] = hm_b1[j] + sum_e traj[t,e]*hm_w1[512+e][j]
//   blocks 8..15  : avp[t][j]    = ab1[j]   + sum_e traj[t,e]*aw1[512+e][j]
//   block  16     : w2f (2048) + b2f (4) -> fp32; writes flag[0]
//   blocks 17..144: W1 -> Bth, bf16 (RNE if fp32 world) in MFMA fragment
//     order (1-pass bf16 GEMM; absmax pinned at 9.8e-4 through exact/3-pass/
//     2-pass/1-pass gemms -> comparison is downstream-dominated):
//     (k,j) -> seg=(j>>4)*16+(k>>5); lane=((k>>3)&3)<<4|(j&15);
//     dst=(seg*64+lane)*8 + (k&7).
//   blocks 145..400: segment-max partials, block=(b, chunk c of 16):
//     partial[(b*16+c)*512+j]
// ---------------------------------------------------------------------------
__global__ __launch_bounds__(256) void prep_conv_kernel(
    const void* __restrict__ hm_w1, const void* __restrict__ hm_b1,
    const void* __restrict__ traj, const void* __restrict__ hm_w2,
    const void* __restrict__ hm_b2, const void* __restrict__ aw1,
    const void* __restrict__ ab1, const void* __restrict__ pe,
    const int* __restrict__ npts, float* __restrict__ vprime,
    float* __restrict__ w2f, float* __restrict__ b2f,
    float* __restrict__ avp, u16* __restrict__ Bth,
    float* __restrict__ partial, int* __restrict__ flag) {
  const int tid = threadIdx.x, blk = blockIdx.x;
  // ---- local sniff (benign-race shared flag, same value from all lanes) ----
  __shared__ int sflag;
  if (tid == 0) sflag = 0;
  __syncthreads();
  {
    const u16* p16 = (const u16*)pe;
    int c = 0;
    for (int i = tid; i < 8192; i += 256)
      if ((p16[i] & 0x7F80u) == 0x7F80u) c = 1;
    if (c) sflag = 1;
  }
  __syncthreads();
  const bool f32 = sflag != 0;
  if (blk < 8) {
    const int t = blk;
    for (int j = tid; j < 512; j += 256) {
      float acc = rd(hm_b1, j, f32);
      for (int e = 0; e < 64; ++e)
        acc = fmaf(rd(traj, t * 64 + e, f32),
                   rd(hm_w1, (size_t)(512 + e) * 512 + j, f32), acc);
      vprime[t * 512 + j] = acc;
    }
  } else if (blk < 16) {
    const int t = blk - 8;
    for (int j = tid; j < 512; j += 256) {
      float acc = rd(ab1, j, f32);
      for (int e = 0; e < 64; ++e)
        acc = fmaf(rd(traj, t * 64 + e, f32),
                   rd(aw1, (size_t)(512 + e) * 512 + j, f32), acc);
      avp[t * 512 + j] = acc;
    }
  } else if (blk == 16) {
    if (tid == 0) flag[0] = f32 ? 1 : 0;  // persist for downstream kernels
    for (int i = tid; i < 2048; i += 256) w2f[i] = rd(hm_w2, i, f32);
    if (tid < 4) b2f[tid] = rd(hm_b2, tid, f32);
  } else if (blk < 145) {
    const int g = (blk - 17) * 256 + tid;  // 0..32767
    const int j = g & 511;
    const int kbase = (g >> 9) * 8;
    const int seg = (j >> 4) * 16 + (kbase >> 5);
    const int lane_ = (((kbase >> 3) & 3) << 4) | (j & 15);
    const size_t dst = ((size_t)seg * 64 + lane_) * 8;
    s16x8 hv;
    if (f32) {
      const float* W1 = (const float*)hm_w1;
#pragma unroll
      for (int i = 0; i < 8; ++i)
        hv[i] = (short)f2bf(W1[(size_t)(kbase + i) * 512 + j]);  // RNE
      *(s16x8*)&Bth[dst] = hv;
    } else {
      const u16* W1 = (const u16*)hm_w1;
#pragma unroll
      for (int i = 0; i < 8; ++i) hv[i] = (short)W1[(size_t)(kbase + i) * 512 + j];
      *(s16x8*)&Bth[dst] = hv;
    }
  } else {
    const int blk2 = blk - 145;
    const int b = blk2 >> 4, c = blk2 & 15;
    int s0 = 0, cnt = 0;
    for (int i = 0; i < 16; ++i) {
      const int v = npts[i];
      if (i < b) s0 += v;
      if (i == b) cnt = v;
    }
    const int chunk = (cnt + 15) >> 4;
    const int r0 = s0 + c * chunk;
    int r1 = r0 + chunk;
    const int rend = s0 + cnt;
    if (r1 > rend) r1 = rend;
    const int j2 = tid;  // covers cols 2*j2, 2*j2+1
    float m0 = -1e30f, m1 = -1e30f;
    if (f32) {
      const float* pf = (const float*)pe;
      for (int n = r0; n < r1; ++n) {
        const float2 v = *(const float2*)(pf + (size_t)n * 512 + 2 * j2);
        m0 = fmaxf(m0, v.x);
        m1 = fmaxf(m1, v.y);
      }
    } else {
      const u32* p32 = (const u32*)pe;
      for (int n = r0; n < r1; ++n) {
        const u32 v = p32[(size_t)n * 256 + j2];
        m0 = fmaxf(m0, bf2f((u16)(v & 0xffffu)));
        m1 = fmaxf(m1, bf2f((u16)(v >> 16)));
      }
    }
    partial[(size_t)blk2 * 512 + 2 * j2] = m0;
    partial[(size_t)blk2 * 512 + 2 * j2 + 1] = m1;
  }
}

// ---------------------------------------------------------------------------
// gemm_fused (BOTH worlds, 1-pass bf16 MFMA GEMM + fused stage2):
//   hidpre = bf16(A) @ bf16(W1)  (fp32 world: A RNE-cast during staging;
//   bf16 world: A copied as-is -- the two paths differ ONLY in staging)
//   per (n,t): hm = lrelu(hidpre[n]+vprime[t]) @ w2 + b2 -> logits, nc
// v4 geometry (proven local optimum): BM=64, 1024 thr = 16 waves, 1 block/CU
// (grid 256 exact), wave = 4rt x 2ct; fully unrolled k-loop.
// NEW: 4-deep named B register pipeline (bh0..bh3). The 1-pass form freed
// ~24 VGPRs (al/bl gone; R14 counters: VGPR 64, MfmaUtil 6.5% = pure B-load
// latency). Live set acc 16 + ah 16 + 4xB 32 + addr ~= 80 < 128 cap, so the
// allocator can keep 8 B-loads in flight/wave (x4 waves/SIMD = 32
// outstanding ~ covers 250cy L2 latency).
// LDS: sAh 64KB inside the 132KB sU region (reused) + sred 8KB + sW2 8KB.
// Fragment mappings (learn_hip m89/m92 verified):
//   A: row=lane&15, k=k0+(lane>>4)*8+i     B: col=lane&15, same k
//   D: col=lane&15, row=(lane>>4)*4+reg
// ---------------------------------------------------------------------------
#define SU_STRIDE 516
__global__ __launch_bounds__(1024, 4) void gemm_fused(
    const void* __restrict__ A, const u16* __restrict__ Bth,
    const float* __restrict__ vprime, const float* __restrict__ w2f,
    const float* __restrict__ b2f, const void* __restrict__ coords,
    float* __restrict__ logits, float* __restrict__ nc,
    const int* __restrict__ flag) {
  const bool f32 = flag[0] != 0;
  __shared__ __attribute__((aligned(16))) char smem[64 * SU_STRIDE * 4];
  __shared__ float4 sred[512];  // 8KB
  __shared__ float sW2[2048];   // 8KB
  u16* sAh = (u16*)smem;  // 64 KB, fragment order
  const int tid = threadIdx.x;
  const int rb = blockIdx.x * 64;
  for (int i = tid; i < 2048; i += 1024) sW2[i] = w2f[i];
#pragma unroll
  for (int it = 0; it < 4; ++it) {
    const int c = tid + it * 1024;  // 0..4095
    const int row = ((c >> 10) << 4) | (c & 15);
    const int kc = (((c >> 6) & 15) << 2) | ((c >> 4) & 3);
    if (f32) {
      const float* src = (const float*)A + (size_t)(rb + row) * 512 + kc * 8;
      const float4 x0 = *(const float4*)(src);
      const float4 x1 = *(const float4*)(src + 4);
      const float xs[8] = {x0.x, x0.y, x0.z, x0.w, x1.x, x1.y, x1.z, x1.w};
      s16x8 hv;
#pragma unroll
      for (int i = 0; i < 8; ++i) hv[i] = (short)f2bf(xs[i]);  // RNE
      *(s16x8*)&sAh[c * 8] = hv;
    } else {
      *(s16x8*)&sAh[c * 8] =
          *(const s16x8*)((const u16*)A + (size_t)(rb + row) * 512 + kc * 8);
    }
  }
  __syncthreads();
  const int wave = tid >> 6, lane = tid & 63;
  f32x4 acc[4][2];
#pragma unroll
  for (int rt = 0; rt < 4; ++rt)
#pragma unroll
    for (int ct = 0; ct < 2; ++ct) acc[rt][ct] = (f32x4){0.f, 0.f, 0.f, 0.f};
  const int bbase = (wave * 2 * 16 * 64 + lane) * 8;
#define LDB(H, ks)                                                             \
  {                                                                            \
    H[0] = *(const s16x8*)&Bth[bbase + (ks) * 512];                            \
    H[1] = *(const s16x8*)&Bth[bbase + 8192 + (ks) * 512];                     \
  }
#define LDA(ks)                                                                \
  {                                                                            \
    _Pragma("unroll") for (int rt = 0; rt < 4; ++rt) {                         \
      const int aoff = ((rt * 16 + (ks)) * 64 + lane) * 8;                     \
      ah[rt] = *(const s16x8*)&sAh[aoff];                                      \
    }                                                                          \
  }
#define MM(H)                                                                  \
  _Pragma("unroll") for (int rt = 0; rt < 4; ++rt)                             \
      _Pragma("unroll") for (int ct = 0; ct < 2; ++ct) {                       \
    acc[rt][ct] = __builtin_amdgcn_mfma_f32_16x16x32_bf16(ah[rt], H[ct],       \
                                                          acc[rt][ct], 0, 0,   \
                                                          0);                  \
  }
  {
    s16x8 ah[4];
    s16x8 bh0[2], bh1[2], bh2[2], bh3[2];
    LDB(bh0, 0);
    LDB(bh1, 1);
    LDB(bh2, 2);
#pragma unroll
    for (int ks = 0; ks < 16; ks += 4) {
      LDB(bh3, ks + 3);
      LDA(ks);
      MM(bh0);
      if (ks + 4 < 16) LDB(bh0, ks + 4);
      LDA(ks + 1);
      MM(bh1);
      if (ks + 5 < 16) LDB(bh1, ks + 5);
      LDA(ks + 2);
      MM(bh2);
      if (ks + 6 < 16) LDB(bh2, ks + 6);
      LDA(ks + 3);
      MM(bh3);
    }
  }
#undef LDB
#undef LDA
#undef MM
  __syncthreads();  // all ds_reads of sAh done; safe to overwrite
  float* sU = (float*)smem;
  const int lr = lane & 15, orow = (lane >> 4) * 4;
#pragma unroll
  for (int rt = 0; rt < 4; ++rt)
#pragma unroll
    for (int ct = 0; ct < 2; ++ct) {
      const int col = (wave * 2 + ct) * 16 + lr;
#pragma unroll
      for (int r = 0; r < 4; ++r)
        sU[(rt * 16 + orow + r) * SU_STRIDE + col] = acc[rt][ct][r];
    }
  __syncthreads();
  const int p = tid & 511, half = tid >> 9;
  const int ln = p >> 3, t = p & 7;
  const int n = rb + ln;
  const float* su = sU + ln * SU_STRIDE + half * 256;
  const float* vp = vprime + t * 512 + half * 256;
  const float4* w4 = (const float4*)sW2 + half * 64 * 4;
  float a0 = 0.f, a1 = 0.f, a2 = 0.f, a3 = 0.f;
#pragma unroll 4
  for (int j4 = 0; j4 < 64; ++j4) {
    const float4 uu = *(const float4*)(su + j4 * 4);
    const float4 vv = *(const float4*)(vp + j4 * 4);
    const float4 w_0 = w4[j4 * 4 + 0];
    const float4 w_1 = w4[j4 * 4 + 1];
    const float4 w_2 = w4[j4 * 4 + 2];
    const float4 w_3 = w4[j4 * 4 + 3];
    float h;
    h = lrelu(uu.x + vv.x);
    a0 = fmaf(h, w_0.x, a0); a1 = fmaf(h, w_0.y, a1);
    a2 = fmaf(h, w_0.z, a2); a3 = fmaf(h, w_0.w, a3);
    h = lrelu(uu.y + vv.y);
    a0 = fmaf(h, w_1.x, a0); a1 = fmaf(h, w_1.y, a1);
    a2 = fmaf(h, w_1.z, a2); a3 = fmaf(h, w_1.w, a3);
    h = lrelu(uu.z + vv.z);
    a0 = fmaf(h, w_2.x, a0); a1 = fmaf(h, w_2.y, a1);
    a2 = fmaf(h, w_2.z, a2); a3 = fmaf(h, w_2.w, a3);
    h = lrelu(uu.w + vv.w);
    a0 = fmaf(h, w_3.x, a0); a1 = fmaf(h, w_3.y, a1);
    a2 = fmaf(h, w_3.z, a2); a3 = fmaf(h, w_3.w, a3);
  }
  if (half) sred[p] = make_float4(a0, a1, a2, a3);
  __syncthreads();
  if (!half) {
    const float4 r = sred[p];
    a0 += r.x; a1 += r.y; a2 += r.z; a3 += r.w;
    logits[(size_t)n * 8 + t] = a0 + b2f[0];
    float* o = nc + ((size_t)n * 8 + t) * 3;
    o[0] = rd(coords, (size_t)n * 3 + 0, f32) + a1 + b2f[1];
    o[1] = rd(coords, (size_t)n * 3 + 1, f32) + a2 + b2f[2];
    o[2] = rd(coords, (size_t)n * 3 + 2, f32) + a3 + b2f[3];
  }
}

// ---------------------------------------------------------------------------
// softact (merged; one launch):
//   blocks 0..127  : per-(b,t) softmax + weighted coord sum -> xt
//   blocks 128..255: act_hid: hid[b][t][j] = lrelu(pc[b]@aw1 + avp[t])[j]
// ---------------------------------------------------------------------------
__global__ __launch_bounds__(256) void softact_kernel(
    const float* __restrict__ logits, const float* __restrict__ nc,
    const int* __restrict__ npts, const float* __restrict__ partial,
    const void* __restrict__ aw1, const float* __restrict__ avp,
    float* __restrict__ hid, void* __restrict__ out,
    const int* __restrict__ flag) {
  const bool f32 = flag[0] != 0;
  const int tid = threadIdx.x;
  if (blockIdx.x < 128) {
    const int b = blockIdx.x >> 3, t = blockIdx.x & 7;
    int s0 = 0, cnt = 0;
    for (int i = 0; i < 16; ++i) {
      const int v = npts[i];
      if (i < b) s0 += v;
      if (i == b) cnt = v;
    }
    __shared__ float wm[4];
    __shared__ float red[4][4];
    float m = -1e30f;
    for (int i = tid; i < cnt; i += 256)
      m = fmaxf(m, logits[(size_t)(s0 + i) * 8 + t]);
#pragma unroll
    for (int o = 32; o > 0; o >>= 1) m = fmaxf(m, __shfl_down(m, o, 64));
    if ((tid & 63) == 0) wm[tid >> 6] = m;
    __syncthreads();
    const float mt = fmaxf(fmaxf(wm[0], wm[1]), fmaxf(wm[2], wm[3]));
    float z = 0.f, x = 0.f, y = 0.f, w = 0.f;
    for (int i = tid; i < cnt; i += 256) {
      const size_t g = (size_t)(s0 + i) * 8 + t;
      const float e = expf(logits[g] - mt);
      const float* c3 = nc + g * 3;
      z += e;
      x = fmaf(e, c3[0], x);
      y = fmaf(e, c3[1], y);
      w = fmaf(e, c3[2], w);
    }
#pragma unroll
    for (int o = 32; o > 0; o >>= 1) {
      z += __shfl_down(z, o, 64);
      x += __shfl_down(x, o, 64);
      y += __shfl_down(y, o, 64);
      w += __shfl_down(w, o, 64);
    }
    if ((tid & 63) == 0) {
      red[0][tid >> 6] = z; red[1][tid >> 6] = x;
      red[2][tid >> 6] = y; red[3][tid >> 6] = w;
    }
    __syncthreads();
    if (tid == 0) {
      const float Z = red[0][0] + red[0][1] + red[0][2] + red[0][3];
      const float X = red[1][0] + red[1][1] + red[1][2] + red[1][3];
      const float Y = red[2][0] + red[2][1] + red[2][2] + red[2][3];
      const float W = red[3][0] + red[3][1] + red[3][2] + red[3][3];
      wr(out, (size_t)(b * 8 + t) * 3 + 0, f32, X / Z);
      wr(out, (size_t)(b * 8 + t) * 3 + 1, f32, Y / Z);
      wr(out, (size_t)(b * 8 + t) * 3 + 2, f32, W / Z);
    }
  } else {
    const int blk2 = blockIdx.x - 128;
    const int b = blk2 >> 3, jt = blk2 & 7;
    __shared__ float spc[512];
    __shared__ float sred2[4][64];
    for (int k = tid; k < 512; k += 256) {
      float m = -1e30f;
#pragma unroll
      for (int c = 0; c < 16; ++c)
        m = fmaxf(m, partial[(size_t)(b * 16 + c) * 512 + k]);
      spc[k] = m;
    }
    __syncthreads();
    const int jj = tid & 63, kq = tid >> 6;
    const int j = jt * 64 + jj;
    const int kb = kq * 128;
    float a0 = 0.f, a1 = 0.f, a2 = 0.f, a3 = 0.f;
    if (f32) {
      const float* W = (const float*)aw1 + (size_t)kb * 512 + j;
#pragma unroll 4
      for (int k = 0; k < 128; k += 4) {
        a0 = fmaf(spc[kb + k + 0], W[(size_t)(k + 0) * 512], a0);
        a1 = fmaf(spc[kb + k + 1], W[(size_t)(k + 1) * 512], a1);
        a2 = fmaf(spc[kb + k + 2], W[(size_t)(k + 2) * 512], a2);
        a3 = fmaf(spc[kb + k + 3], W[(size_t)(k + 3) * 512], a3);
      }
    } else {
      const u16* W = (const u16*)aw1 + (size_t)kb * 512 + j;
#pragma unroll 4
      for (int k = 0; k < 128; k += 4) {
        a0 = fmaf(spc[kb + k + 0], bf2f(W[(size_t)(k + 0) * 512]), a0);
        a1 = fmaf(spc[kb + k + 1], bf2f(W[(size_t)(k + 1) * 512]), a1);
        a2 = fmaf(spc[kb + k + 2], bf2f(W[(size_t)(k + 2) * 512]), a2);
        a3 = fmaf(spc[kb + k + 3], bf2f(W[(size_t)(k + 3) * 512]), a3);
      }
    }
    sred2[kq][jj] = (a0 + a1) + (a2 + a3);
    __syncthreads();
    if (kq == 0) {
      const float s = (sred2[0][jj] + sred2[1][jj]) + (sred2[2][jj] + sred2[3][jj]);
#pragma unroll
      for (int t = 0; t < 8; ++t)
        hid[(size_t)(b * 8 + t) * 512 + j] = lrelu(s + avp[t * 512 + j]);
    }
  }
}

// ---------------------------------------------------------------------------
// act_out: ae[row][c] = hid[row] . aw2[:,c] + ab2[c].  Grid = 128 rows.
// ---------------------------------------------------------------------------
__global__ __launch_bounds__(256) void act_out_kernel(
    const float* __restrict__ hid, const void* __restrict__ aw2,
    const void* __restrict__ ab2, void* __restrict__ out,
    const int* __restrict__ flag) {
  const bool f32 = flag[0] != 0;
  __shared__ float sh[512];
  const int row = blockIdx.x, tid = threadIdx.x;
  for (int i = tid; i < 512; i += 256) sh[i] = hid[(size_t)row * 512 + i];
  __syncthreads();
  if (tid < OUTC) {
    float a0 = 0.f, a1 = 0.f, a2 = 0.f, a3 = 0.f;
    if (f32) {
      const float* W = (const float*)aw2 + tid;
#pragma unroll 8
      for (int j = 0; j < 512; j += 4) {
        a0 = fmaf(sh[j + 0], W[(size_t)(j + 0) * OUTC], a0);
        a1 = fmaf(sh[j + 1], W[(size_t)(j + 1) * OUTC], a1);
        a2 = fmaf(sh[j + 2], W[(size_t)(j + 2) * OUTC], a2);
        a3 = fmaf(sh[j + 3], W[(size_t)(j + 3) * OUTC], a3);
      }
    } else {
      const u16* W = (const u16*)aw2 + tid;
#pragma unroll 8
      for (int j = 0; j < 512; j += 4) {
        a0 = fmaf(sh[j + 0], bf2f(W[(size_t)(j + 0) * OUTC]), a0);
        a1 = fmaf(sh[j + 1], bf2f(W[(size_t)(j + 1) * OUTC]), a1);
        a2 = fmaf(sh[j + 2], bf2f(W[(size_t)(j + 2) * OUTC]), a2);
        a3 = fmaf(sh[j + 3], bf2f(W[(size_t)(j + 3) * OUTC]), a3);
      }
    }
    const float o = rd(ab2, tid, f32) + ((a0 + a1) + (a2 + a3));
    if (tid < 216)
      wr(out, 384 + (size_t)row * 216 + tid, f32, o);
    else if (tid == 216)
      wr(out, 384 + 27648 + row, f32, o);
    else
      wr(out, 384 + 27648 + 128 + row, f32, o);
  }
}

// ---------------------------------------------------------------------------
extern "C" void kernel_launch(void* const* d_in, const int* in_sizes, int n_in,
                              void* d_out, int out_size, void* d_ws,
                              size_t ws_size, hipStream_t stream) {
  (void)in_sizes; (void)n_in; (void)out_size; (void)ws_size;
  const void* pe     = d_in[0];
  const void* coords = d_in[1];
  const void* traj   = d_in[2];
  const void* hm_w1  = d_in[3];
  const void* hm_b1  = d_in[4];
  const void* hm_w2  = d_in[5];
  const void* hm_b2  = d_in[6];
  const void* aw1    = d_in[7];
  const void* ab1    = d_in[8];
  const void* aw2    = d_in[9];
  const void* ab2    = d_in[10];
  const int* npts    = (const int*)d_in[11];

  char* ws = (char*)d_ws;
  int*   flag    = (int*)(ws + 0);
  float* avp     = (float*)(ws + 256);        //    8*512*4 = 16384
  float* hid     = (float*)(ws + 16896);      //  128*512*4 = 262144
  u16*   Bth     = (u16*)(ws + 524288);       // 512KB
  float* vprime  = (float*)(ws + 34078720);   //    8*512*4 = 16384
  float* w2f     = (float*)(ws + 34095104);   //     2048*4 = 8192
  float* b2f     = (float*)(ws + 34103296);   //        4*4 (pad to 256)
  float* logits  = (float*)(ws + 34103552);   //  16384*8*4 = 524288
  float* nc      = (float*)(ws + 34627840);   // 16384*8*3*4 = 1572864
  float* partial = (float*)(ws + 36200704);   //  16*16*512*4 = 524288

  prep_conv_kernel<<<401, 256, 0, stream>>>(hm_w1, hm_b1, traj, hm_w2, hm_b2,
                                            aw1, ab1, pe, npts, vprime, w2f,
                                            b2f, avp, Bth, partial, flag);
  gemm_fused<<<NPTS / 64, 1024, 0, stream>>>(pe, Bth, vprime, w2f, b2f,
                                             coords, logits, nc, flag);
  softact_kernel<<<256, 256, 0, stream>>>(logits, nc, npts, partial, aw1, avp,
                                          hid, d_out, flag);
  act_out_kernel<<<128, 256, 0, stream>>>(hid, aw2, ab2, d_out, flag);
}

// Round 16
// 170.330 us; speedup vs baseline: 1.0063x; 1.0063x over previous
//
#include <hip/hip_runtime.h>
#include <math.h>

typedef unsigned short u16;
typedef unsigned int u32;

// Problem constants
#define NPTS 16384
#define HID  512
#define TT   8
#define TE   64
#define NB   16
#define OUTC 218

typedef short s16x8 __attribute__((ext_vector_type(8)));   // 8 bf16 (4 VGPRs)
typedef float f32x4 __attribute__((ext_vector_type(4)));   // MFMA accumulator

__device__ __forceinline__ float bf2f(u16 u) {
  return __uint_as_float(((u32)u) << 16);
}
__device__ __forceinline__ u16 f2bf(float f) {
  u32 x = __float_as_uint(f);
  x += 0x7fffu + ((x >> 16) & 1u);
  return (u16)(x >> 16);
}
__device__ __forceinline__ float lrelu(float h) { return fmaxf(h, 0.02f * h); }

// dtype-adaptive external tensor access (f32 flag sniffed at runtime)
__device__ __forceinline__ float rd(const void* p, size_t i, bool f32) {
  return f32 ? ((const float*)p)[i] : bf2f(((const u16*)p)[i]);
}
__device__ __forceinline__ void wr(void* p, size_t i, bool f32, float v) {
  if (f32) ((float*)p)[i] = v;
  else ((u16*)p)[i] = f2bf(v);
}

// ---------------------------------------------------------------------------
// prep_conv (merged sniff + prep + W1-conv + segmax; one launch):
//   EVERY block first sniffs the dtype locally from pe[0:8192] (fp32 read as
//   bf16 pairs -> ~1/256 of low halves match the Inf/NaN exponent pattern;
//   finite bf16 never matches). 8KB L2-hot scan, no inter-block dependency.
//   Block 16 persists flag[0] for the downstream kernels.
//   blocks 0..7   : vprime[t][j] = hm_b1[j] + sum_e traj[t,e]*hm_w1[512+e][j]
//   blocks 8..15  : avp[t][j]    = ab1[j]   + sum_e traj[t,e]*aw1[512+e][j]
//   block  16     : w2f (2048) + b2f (4) -> fp32; writes flag[0]
//   blocks 17..144: W1 -> Bth, bf16 (RNE if fp32 world) in MFMA fragment
//     order (1-pass bf16 GEMM; absmax pinned at 9.8e-4 through exact/3-pass/
//     2-pass/1-pass gemms -> comparison is downstream-dominated):
//     (k,j) -> seg=(j>>4)*16+(k>>5); lane=((k>>3)&3)<<4|(j&15);
//     dst=(seg*64+lane)*8 + (k&7).
//   blocks 145..400: segment-max partials, block=(b, chunk c of 16):
//     partial[(b*16+c)*512+j]
// ---------------------------------------------------------------------------
__global__ __launch_bounds__(256) void prep_conv_kernel(
    const void* __restrict__ hm_w1, const void* __restrict__ hm_b1,
    const void* __restrict__ traj, const void* __restrict__ hm_w2,
    const void* __restrict__ hm_b2, const void* __restrict__ aw1,
    const void* __restrict__ ab1, const void* __restrict__ pe,
    const int* __restrict__ npts, float* __restrict__ vprime,
    float* __restrict__ w2f, float* __restrict__ b2f,
    float* __restrict__ avp, u16* __restrict__ Bth,
    float* __restrict__ partial, int* __restrict__ flag) {
  const int tid = threadIdx.x, blk = blockIdx.x;
  // ---- local sniff (benign-race shared flag, same value from all lanes) ----
  __shared__ int sflag;
  if (tid == 0) sflag = 0;
  __syncthreads();
  {
    const u16* p16 = (const u16*)pe;
    int c = 0;
    for (int i = tid; i < 8192; i += 256)
      if ((p16[i] & 0x7F80u) == 0x7F80u) c = 1;
    if (c) sflag = 1;
  }
  __syncthreads();
  const bool f32 = sflag != 0;
  if (blk < 8) {
    const int t = blk;
    for (int j = tid; j < 512; j += 256) {
      float acc = rd(hm_b1, j, f32);
      for (int e = 0; e < 64; ++e)
        acc = fmaf(rd(traj, t * 64 + e, f32),
                   rd(hm_w1, (size_t)(512 + e) * 512 + j, f32), acc);
      vprime[t * 512 + j] = acc;
    }
  } else if (blk < 16) {
    const int t = blk - 8;
    for (int j = tid; j < 512; j += 256) {
      float acc = rd(ab1, j, f32);
      for (int e = 0; e < 64; ++e)
        acc = fmaf(rd(traj, t * 64 + e, f32),
                   rd(aw1, (size_t)(512 + e) * 512 + j, f32), acc);
      avp[t * 512 + j] = acc;
    }
  } else if (blk == 16) {
    if (tid == 0) flag[0] = f32 ? 1 : 0;  // persist for downstream kernels
    for (int i = tid; i < 2048; i += 256) w2f[i] = rd(hm_w2, i, f32);
    if (tid < 4) b2f[tid] = rd(hm_b2, tid, f32);
  } else if (blk < 145) {
    const int g = (blk - 17) * 256 + tid;  // 0..32767
    const int j = g & 511;
    const int kbase = (g >> 9) * 8;
    const int seg = (j >> 4) * 16 + (kbase >> 5);
    const int lane_ = (((kbase >> 3) & 3) << 4) | (j & 15);
    const size_t dst = ((size_t)seg * 64 + lane_) * 8;
    s16x8 hv;
    if (f32) {
      const float* W1 = (const float*)hm_w1;
#pragma unroll
      for (int i = 0; i < 8; ++i)
        hv[i] = (short)f2bf(W1[(size_t)(kbase + i) * 512 + j]);  // RNE
      *(s16x8*)&Bth[dst] = hv;
    } else {
      const u16* W1 = (const u16*)hm_w1;
#pragma unroll
      for (int i = 0; i < 8; ++i) hv[i] = (short)W1[(size_t)(kbase + i) * 512 + j];
      *(s16x8*)&Bth[dst] = hv;
    }
  } else {
    const int blk2 = blk - 145;
    const int b = blk2 >> 4, c = blk2 & 15;
    int s0 = 0, cnt = 0;
    for (int i = 0; i < 16; ++i) {
      const int v = npts[i];
      if (i < b) s0 += v;
      if (i == b) cnt = v;
    }
    const int chunk = (cnt + 15) >> 4;
    const int r0 = s0 + c * chunk;
    int r1 = r0 + chunk;
    const int rend = s0 + cnt;
    if (r1 > rend) r1 = rend;
    const int j2 = tid;  // covers cols 2*j2, 2*j2+1
    float m0 = -1e30f, m1 = -1e30f;
    if (f32) {
      const float* pf = (const float*)pe;
      for (int n = r0; n < r1; ++n) {
        const float2 v = *(const float2*)(pf + (size_t)n * 512 + 2 * j2);
        m0 = fmaxf(m0, v.x);
        m1 = fmaxf(m1, v.y);
      }
    } else {
      const u32* p32 = (const u32*)pe;
      for (int n = r0; n < r1; ++n) {
        const u32 v = p32[(size_t)n * 256 + j2];
        m0 = fmaxf(m0, bf2f((u16)(v & 0xffffu)));
        m1 = fmaxf(m1, bf2f((u16)(v >> 16)));
      }
    }
    partial[(size_t)blk2 * 512 + 2 * j2] = m0;
    partial[(size_t)blk2 * 512 + 2 * j2 + 1] = m1;
  }
}

// ---------------------------------------------------------------------------
// gemm_fused (BOTH worlds, 1-pass bf16 MFMA GEMM + fused stage2):
//   hidpre = bf16(A) @ bf16(W1)  (fp32 world: A RNE-cast during staging;
//   bf16 world: A copied as-is -- the two paths differ ONLY in staging)
//   per (n,t): hm = lrelu(hidpre[n]+vprime[t]) @ w2 + b2 -> logits, nc
// v4 geometry (proven local optimum): BM=64, 1024 thr = 16 waves, 1 block/CU
// (grid 256 exact), wave = 4rt x 2ct; fully unrolled k-loop.
// NEW (R16): 8-deep B prefetch with __builtin_amdgcn_sched_barrier(0)
// fences. Eight source-level pipeline attempts failed because the register
// allocator SINKS loads to just-in-time (VGPR stuck at 64, MfmaUtil 6.5%).
// sched_barrier(0) is a hard scheduling fence: the 16 first-half B loads
// issued before it CANNOT be moved past it, forcing them in flight before
// the first MFMA. Live set: 8 B-buf (64) + acc (16) + ah (16) + addr ~= 106
// < 128-VGPR cap of (1024,4) -> no spill (v5's spill was a 64-VGPR cap).
// Two fences only, at phase boundaries (m141 showed pervasive pinning
// regresses; inside each region the scheduler stays free).
// LDS: sAh 64KB inside the 132KB sU region (reused) + sred 8KB + sW2 8KB.
// Fragment mappings (learn_hip m89/m92 verified):
//   A: row=lane&15, k=k0+(lane>>4)*8+i     B: col=lane&15, same k
//   D: col=lane&15, row=(lane>>4)*4+reg
// ---------------------------------------------------------------------------
#define SU_STRIDE 516
__global__ __launch_bounds__(1024, 4) void gemm_fused(
    const void* __restrict__ A, const u16* __restrict__ Bth,
    const float* __restrict__ vprime, const float* __restrict__ w2f,
    const float* __restrict__ b2f, const void* __restrict__ coords,
    float* __restrict__ logits, float* __restrict__ nc,
    const int* __restrict__ flag) {
  const bool f32 = flag[0] != 0;
  __shared__ __attribute__((aligned(16))) char smem[64 * SU_STRIDE * 4];
  __shared__ float4 sred[512];  // 8KB
  __shared__ float sW2[2048];   // 8KB
  u16* sAh = (u16*)smem;  // 64 KB, fragment order
  const int tid = threadIdx.x;
  const int rb = blockIdx.x * 64;
  for (int i = tid; i < 2048; i += 1024) sW2[i] = w2f[i];
#pragma unroll
  for (int it = 0; it < 4; ++it) {
    const int c = tid + it * 1024;  // 0..4095
    const int row = ((c >> 10) << 4) | (c & 15);
    const int kc = (((c >> 6) & 15) << 2) | ((c >> 4) & 3);
    if (f32) {
      const float* src = (const float*)A + (size_t)(rb + row) * 512 + kc * 8;
      const float4 x0 = *(const float4*)(src);
      const float4 x1 = *(const float4*)(src + 4);
      const float xs[8] = {x0.x, x0.y, x0.z, x0.w, x1.x, x1.y, x1.z, x1.w};
      s16x8 hv;
#pragma unroll
      for (int i = 0; i < 8; ++i) hv[i] = (short)f2bf(xs[i]);  // RNE
      *(s16x8*)&sAh[c * 8] = hv;
    } else {
      *(s16x8*)&sAh[c * 8] =
          *(const s16x8*)((const u16*)A + (size_t)(rb + row) * 512 + kc * 8);
    }
  }
  __syncthreads();
  const int wave = tid >> 6, lane = tid & 63;
  f32x4 acc[4][2];
#pragma unroll
  for (int rt = 0; rt < 4; ++rt)
#pragma unroll
    for (int ct = 0; ct < 2; ++ct) acc[rt][ct] = (f32x4){0.f, 0.f, 0.f, 0.f};
  const int bbase = (wave * 2 * 16 * 64 + lane) * 8;
#define LDB(H, ks)                                                             \
  {                                                                            \
    H[0] = *(const s16x8*)&Bth[bbase + (ks) * 512];                            \
    H[1] = *(const s16x8*)&Bth[bbase + 8192 + (ks) * 512];                     \
  }
#define LDA(ks)                                                                \
  {                                                                            \
    _Pragma("unroll") for (int rt = 0; rt < 4; ++rt) {                         \
      const int aoff = ((rt * 16 + (ks)) * 64 + lane) * 8;                     \
      ah[rt] = *(const s16x8*)&sAh[aoff];                                      \
    }                                                                          \
  }
#define MM(H)                                                                  \
  _Pragma("unroll") for (int rt = 0; rt < 4; ++rt)                             \
      _Pragma("unroll") for (int ct = 0; ct < 2; ++ct) {                       \
    acc[rt][ct] = __builtin_amdgcn_mfma_f32_16x16x32_bf16(ah[rt], H[ct],       \
                                                          acc[rt][ct], 0, 0,   \
                                                          0);                  \
  }
  {
    s16x8 ah[4];
    s16x8 b0[2], b1[2], b2[2], b3[2], b4[2], b5[2], b6[2], b7[2];
    // ---- issue ALL first-half B loads (16 in flight) ----
    LDB(b0, 0); LDB(b1, 1); LDB(b2, 2); LDB(b3, 3);
    LDB(b4, 4); LDB(b5, 5); LDB(b6, 6); LDB(b7, 7);
    __builtin_amdgcn_sched_barrier(0);  // hard fence: loads cannot sink
    LDA(0); MM(b0);
    LDA(1); MM(b1);
    LDA(2); MM(b2);
    LDA(3); MM(b3);
    // second-half loads reuse freed buffers; issued during first-half MFMAs
    LDB(b0, 8); LDB(b1, 9); LDB(b2, 10); LDB(b3, 11);
    LDA(4); MM(b4);
    LDA(5); MM(b5);
    LDA(6); MM(b6);
    LDA(7); MM(b7);
    LDB(b4, 12); LDB(b5, 13); LDB(b6, 14); LDB(b7, 15);
    __builtin_amdgcn_sched_barrier(0);  // all second-half loads in flight
    LDA(8);  MM(b0);
    LDA(9);  MM(b1);
    LDA(10); MM(b2);
    LDA(11); MM(b3);
    LDA(12); MM(b4);
    LDA(13); MM(b5);
    LDA(14); MM(b6);
    LDA(15); MM(b7);
  }
#undef LDB
#undef LDA
#undef MM
  __syncthreads();  // all ds_reads of sAh done; safe to overwrite
  float* sU = (float*)smem;
  const int lr = lane & 15, orow = (lane >> 4) * 4;
#pragma unroll
  for (int rt = 0; rt < 4; ++rt)
#pragma unroll
    for (int ct = 0; ct < 2; ++ct) {
      const int col = (wave * 2 + ct) * 16 + lr;
#pragma unroll
      for (int r = 0; r < 4; ++r)
        sU[(rt * 16 + orow + r) * SU_STRIDE + col] = acc[rt][ct][r];
    }
  __syncthreads();
  const int p = tid & 511, half = tid >> 9;
  const int ln = p >> 3, t = p & 7;
  const int n = rb + ln;
  const float* su = sU + ln * SU_STRIDE + half * 256;
  const float* vp = vprime + t * 512 + half * 256;
  const float4* w4 = (const float4*)sW2 + half * 64 * 4;
  float a0 = 0.f, a1 = 0.f, a2 = 0.f, a3 = 0.f;
#pragma unroll 4
  for (int j4 = 0; j4 < 64; ++j4) {
    const float4 uu = *(const float4*)(su + j4 * 4);
    const float4 vv = *(const float4*)(vp + j4 * 4);
    const float4 w_0 = w4[j4 * 4 + 0];
    const float4 w_1 = w4[j4 * 4 + 1];
    const float4 w_2 = w4[j4 * 4 + 2];
    const float4 w_3 = w4[j4 * 4 + 3];
    float h;
    h = lrelu(uu.x + vv.x);
    a0 = fmaf(h, w_0.x, a0); a1 = fmaf(h, w_0.y, a1);
    a2 = fmaf(h, w_0.z, a2); a3 = fmaf(h, w_0.w, a3);
    h = lrelu(uu.y + vv.y);
    a0 = fmaf(h, w_1.x, a0); a1 = fmaf(h, w_1.y, a1);
    a2 = fmaf(h, w_1.z, a2); a3 = fmaf(h, w_1.w, a3);
    h = lrelu(uu.z + vv.z);
    a0 = fmaf(h, w_2.x, a0); a1 = fmaf(h, w_2.y, a1);
    a2 = fmaf(h, w_2.z, a2); a3 = fmaf(h, w_2.w, a3);
    h = lrelu(uu.w + vv.w);
    a0 = fmaf(h, w_3.x, a0); a1 = fmaf(h, w_3.y, a1);
    a2 = fmaf(h, w_3.z, a2); a3 = fmaf(h, w_3.w, a3);
  }
  if (half) sred[p] = make_float4(a0, a1, a2, a3);
  __syncthreads();
  if (!half) {
    const float4 r = sred[p];
    a0 += r.x; a1 += r.y; a2 += r.z; a3 += r.w;
    logits[(size_t)n * 8 + t] = a0 + b2f[0];
    float* o = nc + ((size_t)n * 8 + t) * 3;
    o[0] = rd(coords, (size_t)n * 3 + 0, f32) + a1 + b2f[1];
    o[1] = rd(coords, (size_t)n * 3 + 1, f32) + a2 + b2f[2];
    o[2] = rd(coords, (size_t)n * 3 + 2, f32) + a3 + b2f[3];
  }
}

// ---------------------------------------------------------------------------
// softact (merged; one launch):
//   blocks 0..127  : per-(b,t) softmax + weighted coord sum -> xt
//   blocks 128..255: act_hid: hid[b][t][j] = lrelu(pc[b]@aw1 + avp[t])[j]
// ---------------------------------------------------------------------------
__global__ __launch_bounds__(256) void softact_kernel(
    const float* __restrict__ logits, const float* __restrict__ nc,
    const int* __restrict__ npts, const float* __restrict__ partial,
    const void* __restrict__ aw1, const float* __restrict__ avp,
    float* __restrict__ hid, void* __restrict__ out,
    const int* __restrict__ flag) {
  const bool f32 = flag[0] != 0;
  const int tid = threadIdx.x;
  if (blockIdx.x < 128) {
    const int b = blockIdx.x >> 3, t = blockIdx.x & 7;
    int s0 = 0, cnt = 0;
    for (int i = 0; i < 16; ++i) {
      const int v = npts[i];
      if (i < b) s0 += v;
      if (i == b) cnt = v;
    }
    __shared__ float wm[4];
    __shared__ float red[4][4];
    float m = -1e30f;
    for (int i = tid; i < cnt; i += 256)
      m = fmaxf(m, logits[(size_t)(s0 + i) * 8 + t]);
#pragma unroll
    for (int o = 32; o > 0; o >>= 1) m = fmaxf(m, __shfl_down(m, o, 64));
    if ((tid & 63) == 0) wm[tid >> 6] = m;
    __syncthreads();
    const float mt = fmaxf(fmaxf(wm[0], wm[1]), fmaxf(wm[2], wm[3]));
    float z = 0.f, x = 0.f, y = 0.f, w = 0.f;
    for (int i = tid; i < cnt; i += 256) {
      const size_t g = (size_t)(s0 + i) * 8 + t;
      const float e = expf(logits[g] - mt);
      const float* c3 = nc + g * 3;
      z += e;
      x = fmaf(e, c3[0], x);
      y = fmaf(e, c3[1], y);
      w = fmaf(e, c3[2], w);
    }
#pragma unroll
    for (int o = 32; o > 0; o >>= 1) {
      z += __shfl_down(z, o, 64);
      x += __shfl_down(x, o, 64);
      y += __shfl_down(y, o, 64);
      w += __shfl_down(w, o, 64);
    }
    if ((tid & 63) == 0) {
      red[0][tid >> 6] = z; red[1][tid >> 6] = x;
      red[2][tid >> 6] = y; red[3][tid >> 6] = w;
    }
    __syncthreads();
    if (tid == 0) {
      const float Z = red[0][0] + red[0][1] + red[0][2] + red[0][3];
      const float X = red[1][0] + red[1][1] + red[1][2] + red[1][3];
      const float Y = red[2][0] + red[2][1] + red[2][2] + red[2][3];
      const float W = red[3][0] + red[3][1] + red[3][2] + red[3][3];
      wr(out, (size_t)(b * 8 + t) * 3 + 0, f32, X / Z);
      wr(out, (size_t)(b * 8 + t) * 3 + 1, f32, Y / Z);
      wr(out, (size_t)(b * 8 + t) * 3 + 2, f32, W / Z);
    }
  } else {
    const int blk2 = blockIdx.x - 128;
    const int b = blk2 >> 3, jt = blk2 & 7;
    __shared__ float spc[512];
    __shared__ float sred2[4][64];
    for (int k = tid; k < 512; k += 256) {
      float m = -1e30f;
#pragma unroll
      for (int c = 0; c < 16; ++c)
        m = fmaxf(m, partial[(size_t)(b * 16 + c) * 512 + k]);
      spc[k] = m;
    }
    __syncthreads();
    const int jj = tid & 63, kq = tid >> 6;
    const int j = jt * 64 + jj;
    const int kb = kq * 128;
    float a0 = 0.f, a1 = 0.f, a2 = 0.f, a3 = 0.f;
    if (f32) {
      const float* W = (const float*)aw1 + (size_t)kb * 512 + j;
#pragma unroll 4
      for (int k = 0; k < 128; k += 4) {
        a0 = fmaf(spc[kb + k + 0], W[(size_t)(k + 0) * 512], a0);
        a1 = fmaf(spc[kb + k + 1], W[(size_t)(k + 1) * 512], a1);
        a2 = fmaf(spc[kb + k + 2], W[(size_t)(k + 2) * 512], a2);
        a3 = fmaf(spc[kb + k + 3], W[(size_t)(k + 3) * 512], a3);
      }
    } else {
      const u16* W = (const u16*)aw1 + (size_t)kb * 512 + j;
#pragma unroll 4
      for (int k = 0; k < 128; k += 4) {
        a0 = fmaf(spc[kb + k + 0], bf2f(W[(size_t)(k + 0) * 512]), a0);
        a1 = fmaf(spc[kb + k + 1], bf2f(W[(size_t)(k + 1) * 512]), a1);
        a2 = fmaf(spc[kb + k + 2], bf2f(W[(size_t)(k + 2) * 512]), a2);
        a3 = fmaf(spc[kb + k + 3], bf2f(W[(size_t)(k + 3) * 512]), a3);
      }
    }
    sred2[kq][jj] = (a0 + a1) + (a2 + a3);
    __syncthreads();
    if (kq == 0) {
      const float s = (sred2[0][jj] + sred2[1][jj]) + (sred2[2][jj] + sred2[3][jj]);
#pragma unroll
      for (int t = 0; t < 8; ++t)
        hid[(size_t)(b * 8 + t) * 512 + j] = lrelu(s + avp[t * 512 + j]);
    }
  }
}

// ---------------------------------------------------------------------------
// act_out: ae[row][c] = hid[row] . aw2[:,c] + ab2[c].  Grid = 128 rows.
// ---------------------------------------------------------------------------
__global__ __launch_bounds__(256) void act_out_kernel(
    const float* __restrict__ hid, const void* __restrict__ aw2,
    const void* __restrict__ ab2, void* __restrict__ out,
    const int* __restrict__ flag) {
  const bool f32 = flag[0] != 0;
  __shared__ float sh[512];
  const int row = blockIdx.x, tid = threadIdx.x;
  for (int i = tid; i < 512; i += 256) sh[i] = hid[(size_t)row * 512 + i];
  __syncthreads();
  if (tid < OUTC) {
    float a0 = 0.f, a1 = 0.f, a2 = 0.f, a3 = 0.f;
    if (f32) {
      const float* W = (const float*)aw2 + tid;
#pragma unroll 8
      for (int j = 0; j < 512; j += 4) {
        a0 = fmaf(sh[j + 0], W[(size_t)(j + 0) * OUTC], a0);
        a1 = fmaf(sh[j + 1], W[(size_t)(j + 1) * OUTC], a1);
        a2 = fmaf(sh[j + 2], W[(size_t)(j + 2) * OUTC], a2);
        a3 = fmaf(sh[j + 3], W[(size_t)(j + 3) * OUTC], a3);
      }
    } else {
      const u16* W = (const u16*)aw2 + tid;
#pragma unroll 8
      for (int j = 0; j < 512; j += 4) {
        a0 = fmaf(sh[j + 0], bf2f(W[(size_t)(j + 0) * OUTC]), a0);
        a1 = fmaf(sh[j + 1], bf2f(W[(size_t)(j + 1) * OUTC]), a1);
        a2 = fmaf(sh[j + 2], bf2f(W[(size_t)(j + 2) * OUTC]), a2);
        a3 = fmaf(sh[j + 3], bf2f(W[(size_t)(j + 3) * OUTC]), a3);
      }
    }
    const float o = rd(ab2, tid, f32) + ((a0 + a1) + (a2 + a3));
    if (tid < 216)
      wr(out, 384 + (size_t)row * 216 + tid, f32, o);
    else if (tid == 216)
      wr(out, 384 + 27648 + row, f32, o);
    else
      wr(out, 384 + 27648 + 128 + row, f32, o);
  }
}

// ---------------------------------------------------------------------------
extern "C" void kernel_launch(void* const* d_in, const int* in_sizes, int n_in,
                              void* d_out, int out_size, void* d_ws,
                              size_t ws_size, hipStream_t stream) {
  (void)in_sizes; (void)n_in; (void)out_size; (void)ws_size;
  const void* pe     = d_in[0];
  const void* coords = d_in[1];
  const void* traj   = d_in[2];
  const void* hm_w1  = d_in[3];
  const void* hm_b1  = d_in[4];
  const void* hm_w2  = d_in[5];
  const void* hm_b2  = d_in[6];
  const void* aw1    = d_in[7];
  const void* ab1    = d_in[8];
  const void* aw2    = d_in[9];
  const void* ab2    = d_in[10];
  const int* npts    = (const int*)d_in[11];

  char* ws = (char*)d_ws;
  int*   flag    = (int*)(ws + 0);
  float* avp     = (float*)(ws + 256);        //    8*512*4 = 16384
  float* hid     = (float*)(ws + 16896);      //  128*512*4 = 262144
  u16*   Bth     = (u16*)(ws + 524288);       // 512KB
  float* vprime  = (float*)(ws + 34078720);   //    8*512*4 = 16384
  float* w2f     = (float*)(ws + 34095104);   //     2048*4 = 8192
  float* b2f     = (float*)(ws + 34103296);   //        4*4 (pad to 256)
  float* logits  = (float*)(ws + 34103552);   //  16384*8*4 = 524288
  float* nc      = (float*)(ws + 34627840);   // 16384*8*3*4 = 1572864
  float* partial = (float*)(ws + 36200704);   //  16*16*512*4 = 524288

  prep_conv_kernel<<<401, 256, 0, stream>>>(hm_w1, hm_b1, traj, hm_w2, hm_b2,
                                            aw1, ab1, pe, npts, vprime, w2f,
                                            b2f, avp, Bth, partial, flag);
  gemm_fused<<<NPTS / 64, 1024, 0, stream>>>(pe, Bth, vprime, w2f, b2f,
                                             coords, logits, nc, flag);
  softact_kernel<<<256, 256, 0, stream>>>(logits, nc, npts, partial, aw1, avp,
                                          hid, d_out, flag);
  act_out_kernel<<<128, 256, 0, stream>>>(hid, aw2, ab2, d_out, flag);
}